// Round 1
// baseline (1180.816 us; speedup 1.0000x reference)
//
#include <hip/hip_runtime.h>

typedef unsigned short u16;
typedef unsigned int u32;
typedef __attribute__((ext_vector_type(4))) float f32x4;
typedef __attribute__((ext_vector_type(8))) short short8;
typedef __attribute__((ext_vector_type(4))) u16 u16x4;

#define N_TOK 16384
#define C_DIM 768
#define I_DIM 1536
#define N_EXP 16
#define TM 128
#define BK 64
#define LSTR 80      // LDS row stride in elems (160B, 16B-aligned, breaks pow2)
#define MAXT 400     // worst-case tile count: 256+16 routed + 128 shared

// ctrl region int offsets (all inside first 1MB of ws)
#define CI_COUNTS 0
#define CI_STARTS 32
#define CI_NTILES 64
#define CI_TILE_E 128
#define CI_TILE_R 640
#define CI_ESLOT 2048        // [N][2] packed (e<<24)|slot
#define CI_SLOT 34816        // [N][2] global padded row index
#define CI_TOKW 67584        // [N][2] float weights
#define CI_PERM 100352       // [51200] row -> token

#define XB_OFF  (1u << 20)          // bf16 x, 25,165,824 B
#define ACT_OFF 26214400u           // bf16 act, 51200*1536*2 = 157,286,400 B
#define Y_OFF   183500800u          // bf16 y,   51200*768*2 =  78,643,200 B
// total ws use: 262,144,000 B

__device__ __forceinline__ u16 f2bf(float f) {
  u32 x = __float_as_uint(f);
  return (u16)((x + 0x7FFFu + ((x >> 16) & 1u)) >> 16);  // RNE
}
__device__ __forceinline__ float bf2f(u16 h) {
  return __uint_as_float(((u32)h) << 16);
}

// ---------------- router: logits, top-2, weights, counts; also casts x->bf16
__global__ void router_kernel(const float* __restrict__ x, const float* __restrict__ wgate,
                              const float* __restrict__ ebias, int* __restrict__ ctrl,
                              u16* __restrict__ xb) {
  __shared__ float xs[16 * 772];        // 16 tokens, padded row (+4) to dodge bank aliasing
  __shared__ float wgs[C_DIM * 16];
  __shared__ float lg[16 * 16];
  int tid = threadIdx.x;
  int tok0 = blockIdx.x * 16;
  const float4* xsrc = (const float4*)(x + (size_t)tok0 * C_DIM);
  const float4* wsrc = (const float4*)wgate;
  float4* wdst = (float4*)wgs;
#pragma unroll
  for (int j = 0; j < 12; j++) {
    int q = tid + j * 256;              // float4 unit, 0..3071
    float4 v = xsrc[q];
    int tk = q / 192;
    int c4 = q - tk * 192;
    *(float4*)&xs[tk * 772 + c4 * 4] = v;
    u16x4 o; o.x = f2bf(v.x); o.y = f2bf(v.y); o.z = f2bf(v.z); o.w = f2bf(v.w);
    *(u16x4*)(xb + (size_t)tok0 * C_DIM + (size_t)q * 4) = o;   // fused x->bf16 cast
    wdst[q] = wsrc[q];
  }
  __syncthreads();
  int tk = tid >> 4, e = tid & 15;
  float acc = ebias[e];
  const float* xrow = &xs[tk * 772];
  for (int c = 0; c < C_DIM; c++) acc = fmaf(xrow[c], wgs[c * 16 + e], acc);
  lg[tk * 16 + e] = acc;
  __syncthreads();
  if (tid < 16) {
    int n = tok0 + tid;
    float l0 = -1e30f, l1 = -1e30f; int i0 = 0, i1 = 0;
#pragma unroll
    for (int j = 0; j < 16; j++) {
      float l = lg[tid * 16 + j];
      if (l > l0) { l1 = l0; i1 = i0; l0 = l; i0 = j; }
      else if (l > l1) { l1 = l; i1 = j; }
    }
    // renormalized top-2 softmax == softmax over {l0,l1}
    float e1 = __expf(l1 - l0);
    float inv = 1.f / (1.f + e1);
    int s0 = atomicAdd(&ctrl[CI_COUNTS + i0], 1);
    int s1 = atomicAdd(&ctrl[CI_COUNTS + i1], 1);
    ctrl[CI_ESLOT + 2 * n]     = (i0 << 24) | s0;
    ctrl[CI_ESLOT + 2 * n + 1] = (i1 << 24) | s1;
    float* tw = (float*)(ctrl + CI_TOKW);
    tw[2 * n] = inv; tw[2 * n + 1] = e1 * inv;
  }
}

// ---------------- segment starts (padded to 128) + tile map; shared = expert 16
__global__ void tiles_kernel(int* __restrict__ ctrl) {
  if (threadIdx.x != 0) return;
  int cnt[17];
#pragma unroll
  for (int e = 0; e < 16; e++) cnt[e] = ctrl[CI_COUNTS + e];
  cnt[16] = N_TOK;
  ctrl[CI_COUNTS + 16] = N_TOK;
  int cur = 0, T = 0;
  for (int e = 0; e <= 16; e++) {
    ctrl[CI_STARTS + e] = cur;
    int nt = (cnt[e] + TM - 1) >> 7;
    for (int i = 0; i < nt; i++) {
      ctrl[CI_TILE_E + T] = e;
      ctrl[CI_TILE_R + T] = cur + i * TM;
      T++;
    }
    cur += nt << 7;
  }
  ctrl[CI_NTILES] = T;
}

// ---------------- scatter token -> padded row (perm + per-token slot)
__global__ void scatter_kernel(int* __restrict__ ctrl) {
  int n = blockIdx.x * 256 + threadIdx.x;
#pragma unroll
  for (int k = 0; k < 2; k++) {
    int es = ctrl[CI_ESLOT + 2 * n + k];
    int e = es >> 24;
    int slot = es & 0xFFFFFF;
    int row = ctrl[CI_STARTS + e] + slot;
    ctrl[CI_PERM + row] = n;
    ctrl[CI_SLOT + 2 * n + k] = row;
  }
}

// ---------------- GEMM1: act = silu(x@Wg) * (x@Wu), gathered rows, fused
__global__ __launch_bounds__(256, 2)
void gemm1_kernel(const u16* __restrict__ xb, const float* __restrict__ wg,
                  const float* __restrict__ wu, const float* __restrict__ swg,
                  const float* __restrict__ swu, u16* __restrict__ act,
                  const int* __restrict__ ctrl) {
  __shared__ u16 Al[TM * LSTR];
  __shared__ u16 Bg[TM * LSTR];
  __shared__ u16 Bu[TM * LSTR];
  int t = blockIdx.x;
  if (t >= ctrl[CI_NTILES]) return;
  int e = ctrl[CI_TILE_E + t];
  int row0 = ctrl[CI_TILE_R + t];
  int col0 = blockIdx.y * TM;
  int seg_start = ctrl[CI_STARTS + e];
  bool sh = (e == N_EXP);
  const float* G; const float* U;
  if (sh) { G = swg; U = swu; }
  else { G = wg + (size_t)e * C_DIM * I_DIM; U = wu + (size_t)e * C_DIM * I_DIM; }
  int row_lim = sh ? 0x7fffffff : (seg_start + ctrl[CI_COUNTS + e]);
  const int* perm = ctrl + CI_PERM;
  int tid = threadIdx.x;
  int tok[4];
#pragma unroll
  for (int j = 0; j < 4; j++) {          // padding rows -> token 0 (harmless garbage)
    int r_loc = (tid + j * 256) >> 3;
    int r = row0 + r_loc;
    tok[j] = sh ? (r - seg_start) : ((r < row_lim) ? perm[r] : 0);
  }
  f32x4 accg[4][4], accu[4][4];
#pragma unroll
  for (int m = 0; m < 4; m++)
#pragma unroll
    for (int n = 0; n < 4; n++) {
      f32x4 z = {0.f, 0.f, 0.f, 0.f};
      accg[m][n] = z; accu[m][n] = z;
    }
  int lane = tid & 63, wv = tid >> 6;
  int rh = (wv & 1) * 64, chh = (wv >> 1) * 64;
  int lr = lane & 15, lq = lane >> 4;

  for (int kk = 0; kk < C_DIM; kk += BK) {
    // stage A (bf16 x rows, gathered): 128 rows x 64k, 16B chunks, XOR-swizzled
#pragma unroll
    for (int j = 0; j < 4; j++) {
      int ch = tid + j * 256;
      int r_loc = ch >> 3;
      int c = ch & 7;
      int p = c ^ (r_loc & 7);
      float4 v = *(const float4*)(xb + (size_t)tok[j] * C_DIM + kk + c * 8);
      *(float4*)&Al[r_loc * LSTR + p * 8] = v;
    }
    // stage Bg/Bu: fp32 [k][i] global -> bf16 [i][k] LDS (transpose + convert)
#pragma unroll 2
    for (int j = 0; j < 8; j++) {
      int u = tid + j * 256;             // 0..2047
      int i = u & 127;
      int k4 = u >> 7;                   // 0..15 (4 k-rows each)
      size_t gb = (size_t)(kk + k4 * 4) * I_DIM + col0 + i;
      float g0 = G[gb], g1 = G[gb + I_DIM], g2 = G[gb + 2 * I_DIM], g3 = G[gb + 3 * I_DIM];
      float h0 = U[gb], h1 = U[gb + I_DIM], h2 = U[gb + 2 * I_DIM], h3 = U[gb + 3 * I_DIM];
      int off = i * LSTR + (((k4 >> 1) ^ (i & 7)) * 8) + (k4 & 1) * 4;
      u16x4 pg; pg.x = f2bf(g0); pg.y = f2bf(g1); pg.z = f2bf(g2); pg.w = f2bf(g3);
      u16x4 pu; pu.x = f2bf(h0); pu.y = f2bf(h1); pu.z = f2bf(h2); pu.w = f2bf(h3);
      *(u16x4*)&Bg[off] = pg;
      *(u16x4*)&Bu[off] = pu;
    }
    __syncthreads();
#pragma unroll
    for (int s = 0; s < 2; s++) {
      int cidx = s * 4 + lq;
      short8 af[4], bg_[4], bu_[4];
#pragma unroll
      for (int m = 0; m < 4; m++) {
        int r = rh + m * 16 + lr;
        af[m] = *(const short8*)&Al[r * LSTR + ((cidx ^ (r & 7)) * 8)];
      }
#pragma unroll
      for (int n = 0; n < 4; n++) {
        int i = chh + n * 16 + lr;
        int off = i * LSTR + ((cidx ^ (i & 7)) * 8);
        bg_[n] = *(const short8*)&Bg[off];
        bu_[n] = *(const short8*)&Bu[off];
      }
#pragma unroll
      for (int m = 0; m < 4; m++)
#pragma unroll
        for (int n = 0; n < 4; n++) {
          accg[m][n] = __builtin_amdgcn_mfma_f32_16x16x32_bf16(af[m], bg_[n], accg[m][n], 0, 0, 0);
          accu[m][n] = __builtin_amdgcn_mfma_f32_16x16x32_bf16(af[m], bu_[n], accu[m][n], 0, 0, 0);
        }
    }
    __syncthreads();
  }
  // epilogue: silu(g)*u -> act (bf16). C/D layout: col=lane&15, row=quad*4+reg
#pragma unroll
  for (int m = 0; m < 4; m++)
#pragma unroll
    for (int n = 0; n < 4; n++)
#pragma unroll
      for (int rg = 0; rg < 4; rg++) {
        float g = accg[m][n][rg];
        float h = accu[m][n][rg];
        float a = g * (1.f / (1.f + __expf(-g))) * h;
        int r_loc = rh + m * 16 + lq * 4 + rg;
        int cl = col0 + chh + n * 16 + lr;
        act[(size_t)(row0 + r_loc) * I_DIM + cl] = f2bf(a);
      }
}

// ---------------- GEMM2: y = act @ Wd (padded layout, no indirection)
__global__ __launch_bounds__(256, 2)
void gemm2_kernel(const u16* __restrict__ act, const float* __restrict__ wd,
                  const float* __restrict__ swd, u16* __restrict__ y,
                  const int* __restrict__ ctrl) {
  __shared__ u16 Al[TM * LSTR];
  __shared__ u16 Bl[TM * LSTR];
  int t = blockIdx.x;
  if (t >= ctrl[CI_NTILES]) return;
  int e = ctrl[CI_TILE_E + t];
  int row0 = ctrl[CI_TILE_R + t];
  int col0 = blockIdx.y * TM;     // over C
  const float* D = (e == N_EXP) ? swd : (wd + (size_t)e * I_DIM * C_DIM);
  int tid = threadIdx.x;
  f32x4 acc[4][4];
#pragma unroll
  for (int m = 0; m < 4; m++)
#pragma unroll
    for (int n = 0; n < 4; n++) {
      f32x4 z = {0.f, 0.f, 0.f, 0.f};
      acc[m][n] = z;
    }
  int lane = tid & 63, wv = tid >> 6;
  int rh = (wv & 1) * 64, chh = (wv >> 1) * 64;
  int lr = lane & 15, lq = lane >> 4;

  for (int kk = 0; kk < I_DIM; kk += BK) {
#pragma unroll
    for (int j = 0; j < 4; j++) {
      int ch = tid + j * 256;
      int r_loc = ch >> 3;
      int c = ch & 7;
      int p = c ^ (r_loc & 7);
      float4 v = *(const float4*)(act + (size_t)(row0 + r_loc) * I_DIM + kk + c * 8);
      *(float4*)&Al[r_loc * LSTR + p * 8] = v;
    }
#pragma unroll 2
    for (int j = 0; j < 8; j++) {
      int u = tid + j * 256;
      int i = u & 127;
      int k4 = u >> 7;
      size_t gb = (size_t)(kk + k4 * 4) * C_DIM + col0 + i;
      float g0 = D[gb], g1 = D[gb + C_DIM], g2 = D[gb + 2 * C_DIM], g3 = D[gb + 3 * C_DIM];
      int off = i * LSTR + (((k4 >> 1) ^ (i & 7)) * 8) + (k4 & 1) * 4;
      u16x4 pg; pg.x = f2bf(g0); pg.y = f2bf(g1); pg.z = f2bf(g2); pg.w = f2bf(g3);
      *(u16x4*)&Bl[off] = pg;
    }
    __syncthreads();
#pragma unroll
    for (int s = 0; s < 2; s++) {
      int cidx = s * 4 + lq;
      short8 af[4], bf_[4];
#pragma unroll
      for (int m = 0; m < 4; m++) {
        int r = rh + m * 16 + lr;
        af[m] = *(const short8*)&Al[r * LSTR + ((cidx ^ (r & 7)) * 8)];
      }
#pragma unroll
      for (int n = 0; n < 4; n++) {
        int i = chh + n * 16 + lr;
        bf_[n] = *(const short8*)&Bl[i * LSTR + ((cidx ^ (i & 7)) * 8)];
      }
#pragma unroll
      for (int m = 0; m < 4; m++)
#pragma unroll
        for (int n = 0; n < 4; n++)
          acc[m][n] = __builtin_amdgcn_mfma_f32_16x16x32_bf16(af[m], bf_[n], acc[m][n], 0, 0, 0);
    }
    __syncthreads();
  }
#pragma unroll
  for (int m = 0; m < 4; m++)
#pragma unroll
    for (int n = 0; n < 4; n++)
#pragma unroll
      for (int rg = 0; rg < 4; rg++) {
        int r_loc = rh + m * 16 + lq * 4 + rg;
        int cl = col0 + chh + n * 16 + lr;
        y[(size_t)(row0 + r_loc) * C_DIM + cl] = f2bf(acc[m][n][rg]);
      }
}

// ---------------- combine: out = y_shared + w0*y0 + w1*y1
__global__ void combine_kernel(const u16* __restrict__ y, const int* __restrict__ ctrl,
                               float* __restrict__ out) {
  int idx = blockIdx.x * 256 + threadIdx.x;  // float4 unit, < N*C/4
  int n = idx / 192;
  int c = (idx - n * 192) * 4;
  int srow = ctrl[CI_STARTS + 16] + n;
  int s0 = ctrl[CI_SLOT + 2 * n];
  int s1 = ctrl[CI_SLOT + 2 * n + 1];
  const float* tw = (const float*)(ctrl + CI_TOKW);
  float w0 = tw[2 * n], w1 = tw[2 * n + 1];
  u16x4 a = *(const u16x4*)(y + (size_t)srow * C_DIM + c);
  u16x4 b = *(const u16x4*)(y + (size_t)s0 * C_DIM + c);
  u16x4 d = *(const u16x4*)(y + (size_t)s1 * C_DIM + c);
  float4 o;
  o.x = bf2f(a.x) + w0 * bf2f(b.x) + w1 * bf2f(d.x);
  o.y = bf2f(a.y) + w0 * bf2f(b.y) + w1 * bf2f(d.y);
  o.z = bf2f(a.z) + w0 * bf2f(b.z) + w1 * bf2f(d.z);
  o.w = bf2f(a.w) + w0 * bf2f(b.w) + w1 * bf2f(d.w);
  *(float4*)(out + (size_t)idx * 4) = o;
}

extern "C" void kernel_launch(void* const* d_in, const int* in_sizes, int n_in,
                              void* d_out, int out_size, void* d_ws, size_t ws_size,
                              hipStream_t stream) {
  (void)in_sizes; (void)n_in; (void)out_size; (void)ws_size;
  const float* x     = (const float*)d_in[0];
  const float* wgate = (const float*)d_in[1];
  const float* ebias = (const float*)d_in[2];
  const float* wg    = (const float*)d_in[3];
  const float* wu    = (const float*)d_in[4];
  const float* wd    = (const float*)d_in[5];
  const float* swg   = (const float*)d_in[6];
  const float* swu   = (const float*)d_in[7];
  const float* swd   = (const float*)d_in[8];
  float* out = (float*)d_out;
  char* ws = (char*)d_ws;
  int* ctrl = (int*)ws;
  u16* xb  = (u16*)(ws + XB_OFF);
  u16* act = (u16*)(ws + ACT_OFF);
  u16* y   = (u16*)(ws + Y_OFF);

  hipMemsetAsync(ws, 0, 256, stream);                       // zero expert counts
  router_kernel<<<N_TOK / 16, 256, 0, stream>>>(x, wgate, ebias, ctrl, xb);
  tiles_kernel<<<1, 64, 0, stream>>>(ctrl);
  scatter_kernel<<<N_TOK / 256, 256, 0, stream>>>(ctrl);
  gemm1_kernel<<<dim3(MAXT, I_DIM / TM), 256, 0, stream>>>(xb, wg, wu, swg, swu, act, ctrl);
  gemm2_kernel<<<dim3(MAXT, C_DIM / TM), 256, 0, stream>>>(act, wd, swd, y, ctrl);
  combine_kernel<<<(N_TOK * C_DIM / 4) / 256, 256, 0, stream>>>(y, ctrl, out);
}

// Round 3
// 1018.175 us; speedup vs baseline: 1.1597x; 1.1597x over previous
//
#include <hip/hip_runtime.h>

typedef unsigned short u16;
typedef unsigned int u32;
typedef __attribute__((ext_vector_type(4))) float f32x4;
typedef __attribute__((ext_vector_type(8))) short short8;
typedef __attribute__((ext_vector_type(4))) u16 u16x4;
typedef __attribute__((ext_vector_type(8))) u16 u16x8;

#define N_TOK 16384
#define C_DIM 768
#define I_DIM 1536
#define N_EXP 16
#define TM 128
#define BK 64
#define MAXT 400        // worst-case tiles: <=272 routed + 128 shared
#define PASS_T 200      // tiles per pass (two passes)

// ctrl region int offsets (first 1MB of ws)
#define CI_COUNTS 0
#define CI_STARTS 32
#define CI_NTILES 64
#define CI_TILE_E 128        // [400]
#define CI_ESLOT 2048        // [N][2] packed (e<<24)|slot
#define CI_TOKW 36864        // [N][2] float weights
#define CI_PERM 102400       // [51200] padded row -> token (-1 = padding)
#define CI_RW 153600         // [51200] float per-row combine weight

// ws layout (bytes) — total 225,181,696 (round-1-proven budget was 262,144,000)
#define XB_OFF  1048576u             // bf16 x: 16384*768*2 = 25,165,824
#define WGU_OFF 26214400u            // bf16 [17][2][I][C] swizzled: 80,216,064
#define WDP_OFF 106430464u           // bf16 [17][C][I] swizzled:    40,108,032
#define ACT_OFF 146538496u           // bf16 act half: 25600*1536*2 = 78,643,200

__device__ __forceinline__ u16 f2bf(float f) {
  u32 x = __float_as_uint(f);
  return (u16)((x + 0x7FFFu + ((x >> 16) & 1u)) >> 16);  // RNE
}
__device__ __forceinline__ float bf2f(u16 h) {
  return __uint_as_float(((u32)h) << 16);
}
__device__ __forceinline__ void dma16(const void* g, void* l) {
  __builtin_amdgcn_global_load_lds(
      (const __attribute__((address_space(1))) unsigned int*)g,
      (__attribute__((address_space(3))) unsigned int*)l, 16, 0, 0);
}

// ---------------- weight convert: fp32 [K][N] -> bf16 [N][K], chunk-XOR swizzle baked.
// Each lane owns one dst row's 64-k block -> 128B contiguous stores (coalesced).
__global__ void convert_kernel(const float* __restrict__ wg, const float* __restrict__ wu,
                               const float* __restrict__ wd, const float* __restrict__ swg,
                               const float* __restrict__ swu, const float* __restrict__ swd,
                               u16* __restrict__ wgu, u16* __restrict__ wdp) {
  int bid = blockIdx.x;
  const float* src; u16* dst; int K, N, base_n;
  if (bid < 34 * 48) {
    int m = bid / 48, nb = bid % 48;
    int e = m >> 1, gu = m & 1;
    src = (e < N_EXP) ? ((gu ? wu : wg) + (size_t)e * C_DIM * I_DIM) : (gu ? swu : swg);
    dst = wgu + (size_t)m * (C_DIM * I_DIM);
    K = C_DIM; N = I_DIM; base_n = nb * 32;
  } else {
    int b2 = bid - 34 * 48;
    int e = b2 / 24, nb = b2 % 24;
    src = (e < N_EXP) ? (wd + (size_t)e * I_DIM * C_DIM) : swd;
    dst = wdp + (size_t)e * (I_DIM * C_DIM);
    K = I_DIM; N = C_DIM; base_n = nb * 32;
  }
  int tid = threadIdx.x, lane = tid & 63, wv = tid >> 6;
  int lsub = lane >> 3, lchk = lane & 7;
  int ng = base_n + wv * 8 + lsub;          // dst row
  int c = lchk ^ (ng & 7);                  // source chunk stored at position lchk
  const float* s0 = src + ng;
  u16* drow = dst + (size_t)ng * K;
  for (int k0 = 0; k0 < K; k0 += 64) {
    u16x8 o;
#pragma unroll
    for (int j = 0; j < 8; j++)
      o[j] = f2bf(s0[(size_t)(k0 + c * 8 + j) * N]);
    *(u16x8*)&drow[k0 + lchk * 8] = o;
  }
}

// ---------------- router: fp32 logits, top-2, weights, counts; also casts x->bf16
__global__ void router_kernel(const float* __restrict__ x, const float* __restrict__ wgate,
                              const float* __restrict__ ebias, int* __restrict__ ctrl,
                              u16* __restrict__ xb) {
  __shared__ float xs[16 * 772];
  __shared__ float wgsT[16 * 772];      // transposed [e][c]
  __shared__ float lg[16 * 16];
  int tid = threadIdx.x;
  int tok0 = blockIdx.x * 16;
  const float4* xsrc = (const float4*)(x + (size_t)tok0 * C_DIM);
  const float4* wsrc = (const float4*)wgate;
#pragma unroll
  for (int j = 0; j < 12; j++) {
    int q = tid + j * 256;              // float4 unit, 0..3071
    float4 v = xsrc[q];
    int tk = q / 192;
    int c4 = q - tk * 192;
    *(float4*)&xs[tk * 772 + c4 * 4] = v;
    u16x4 o; o.x = f2bf(v.x); o.y = f2bf(v.y); o.z = f2bf(v.z); o.w = f2bf(v.w);
    *(u16x4*)(xb + (size_t)tok0 * C_DIM + (size_t)q * 4) = o;   // fused x->bf16 cast
    float4 w = wsrc[q];
    int c = q >> 2, e0 = (q & 3) * 4;
    wgsT[(e0 + 0) * 772 + c] = w.x;
    wgsT[(e0 + 1) * 772 + c] = w.y;
    wgsT[(e0 + 2) * 772 + c] = w.z;
    wgsT[(e0 + 3) * 772 + c] = w.w;
  }
  __syncthreads();
  int tk = tid >> 4, e = tid & 15;
  float acc = ebias[e];
  const float4* xr = (const float4*)&xs[tk * 772];
  const float4* wr = (const float4*)&wgsT[e * 772];
#pragma unroll 4
  for (int c4 = 0; c4 < 192; c4++) {
    float4 xv = xr[c4], wv = wr[c4];
    acc = fmaf(xv.x, wv.x, fmaf(xv.y, wv.y, fmaf(xv.z, wv.z, fmaf(xv.w, wv.w, acc))));
  }
  lg[tk * 16 + e] = acc;
  __syncthreads();
  if (tid < 16) {
    int n = tok0 + tid;
    float l0 = -1e30f, l1 = -1e30f; int i0 = 0, i1 = 0;
#pragma unroll
    for (int j = 0; j < 16; j++) {
      float l = lg[tid * 16 + j];
      if (l > l0) { l1 = l0; i1 = i0; l0 = l; i0 = j; }
      else if (l > l1) { l1 = l; i1 = j; }
    }
    float e1 = __expf(l1 - l0);
    float inv = 1.f / (1.f + e1);
    int s0 = atomicAdd(&ctrl[CI_COUNTS + i0], 1);
    int s1 = atomicAdd(&ctrl[CI_COUNTS + i1], 1);
    ctrl[CI_ESLOT + 2 * n]     = (i0 << 24) | s0;
    ctrl[CI_ESLOT + 2 * n + 1] = (i1 << 24) | s1;
    float* tw = (float*)(ctrl + CI_TOKW);
    tw[2 * n] = inv; tw[2 * n + 1] = e1 * inv;
  }
}

// ---------------- segment starts (padded to 128) + tile->expert map; shared = expert 16
__global__ void tiles_kernel(int* __restrict__ ctrl) {
  if (threadIdx.x != 0) return;
  int cnt[17];
#pragma unroll
  for (int e = 0; e < 16; e++) cnt[e] = ctrl[CI_COUNTS + e];
  cnt[16] = N_TOK;
  ctrl[CI_COUNTS + 16] = N_TOK;
  int cur = 0, T = 0;
  for (int e = 0; e <= 16; e++) {
    ctrl[CI_STARTS + e] = cur;
    int nt = (cnt[e] + TM - 1) >> 7;
    for (int i = 0; i < nt; i++) ctrl[CI_TILE_E + T++] = e;
    cur += nt << 7;
  }
  ctrl[CI_NTILES] = T;
}

// ---------------- scatter: fill perm[row]->token and per-row combine weight
__global__ void scatter_kernel(int* __restrict__ ctrl) {
  int n = blockIdx.x * 256 + threadIdx.x;
  const float* tw = (const float*)(ctrl + CI_TOKW);
  float* rw = (float*)(ctrl + CI_RW);
#pragma unroll
  for (int k = 0; k < 2; k++) {
    int es = ctrl[CI_ESLOT + 2 * n + k];
    int e = es >> 24;
    int slot = es & 0xFFFFFF;
    int row = ctrl[CI_STARTS + e] + slot;
    ctrl[CI_PERM + row] = n;
    rw[row] = tw[2 * n + k];
  }
  int srow = ctrl[CI_STARTS + 16] + n;     // shared expert row
  ctrl[CI_PERM + srow] = n;
  rw[srow] = 1.0f;
}

// ---------------- GEMM1: act = silu(x@Wg) * (x@Wu), gathered rows, DMA staging
__global__ __launch_bounds__(256, 2)
void gemm1_kernel(const u16* __restrict__ xb, const u16* __restrict__ wgu,
                  u16* __restrict__ act, const int* __restrict__ ctrl, int tile0) {
  __shared__ u16 Al[TM * BK];
  __shared__ u16 Bg[TM * BK];
  __shared__ u16 Bu[TM * BK];
  int t = tile0 + blockIdx.x;
  if (t >= ctrl[CI_NTILES]) return;
  int e = ctrl[CI_TILE_E + t];
  int row0 = t << 7;                       // global padded row base
  int row0l = blockIdx.x << 7;             // pass-local row base (act index)
  int col0 = blockIdx.y * TM;
  int seg_start = ctrl[CI_STARTS + e];
  bool sh = (e == N_EXP);
  const u16* G = wgu + (size_t)(2 * e) * (C_DIM * I_DIM);
  const u16* U = G + C_DIM * I_DIM;
  int row_lim = sh ? 0x7fffffff : (seg_start + ctrl[CI_COUNTS + e]);
  const int* perm = ctrl + CI_PERM;
  int tid = threadIdx.x;
  int lane = tid & 63, wv = tid >> 6;
  int lsub = lane >> 3;                    // row within 8-row DMA group
  int lchk = lane & 7;                     // chunk position in LDS
  int co = (lchk ^ lsub) * 8;              // A per-lane swizzled source chunk (elems)
  const u16* aptr[4];
#pragma unroll
  for (int j = 0; j < 4; j++) {
    int r = row0 + wv * 32 + j * 8 + lsub;
    int tok = sh ? (r - seg_start) : ((r < row_lim) ? perm[r] : 0);
    aptr[j] = xb + (size_t)tok * C_DIM + co;
  }
  size_t boff = (size_t)(col0 + wv * 32 + lsub) * C_DIM + lchk * 8;  // swizzle baked in wgu
  int ldst = wv * 2048;                    // u16 elems; + j*512

  f32x4 accg[4][4], accu[4][4];
#pragma unroll
  for (int m = 0; m < 4; m++)
#pragma unroll
    for (int n = 0; n < 4; n++) {
      f32x4 z = {0.f, 0.f, 0.f, 0.f};
      accg[m][n] = z; accu[m][n] = z;
    }
  int lr = lane & 15, lq = lane >> 4;
  int rh = (wv & 1) * 64, chh = (wv >> 1) * 64;

  for (int kk = 0; kk < C_DIM; kk += BK) {
#pragma unroll
    for (int j = 0; j < 4; j++) {
      dma16(aptr[j] + kk,                    Al + ldst + j * 512);
      dma16(G + boff + j * (8 * C_DIM) + kk, Bg + ldst + j * 512);
      dma16(U + boff + j * (8 * C_DIM) + kk, Bu + ldst + j * 512);
    }
    __syncthreads();
#pragma unroll
    for (int s = 0; s < 2; s++) {
      int cidx = s * 4 + lq;
      short8 af[4], bg_[4], bu_[4];
#pragma unroll
      for (int m = 0; m < 4; m++) {
        int r = rh + m * 16 + lr;
        af[m] = *(const short8*)&Al[r * 64 + ((cidx ^ (r & 7)) * 8)];
      }
#pragma unroll
      for (int n = 0; n < 4; n++) {
        int i = chh + n * 16 + lr;
        int off = i * 64 + ((cidx ^ (i & 7)) * 8);
        bg_[n] = *(const short8*)&Bg[off];
        bu_[n] = *(const short8*)&Bu[off];
      }
#pragma unroll
      for (int m = 0; m < 4; m++)
#pragma unroll
        for (int n = 0; n < 4; n++) {
          accg[m][n] = __builtin_amdgcn_mfma_f32_16x16x32_bf16(af[m], bg_[n], accg[m][n], 0, 0, 0);
          accu[m][n] = __builtin_amdgcn_mfma_f32_16x16x32_bf16(af[m], bu_[n], accu[m][n], 0, 0, 0);
        }
    }
    __syncthreads();
  }
#pragma unroll
  for (int m = 0; m < 4; m++)
#pragma unroll
    for (int n = 0; n < 4; n++)
#pragma unroll
      for (int rg = 0; rg < 4; rg++) {
        float g = accg[m][n][rg];
        float h = accu[m][n][rg];
        float a = g * (1.f / (1.f + __expf(-g))) * h;
        int r_loc = rh + m * 16 + lq * 4 + rg;
        int cl = col0 + chh + n * 16 + lr;
        act[(size_t)(row0l + r_loc) * I_DIM + cl] = f2bf(a);
      }
}

// ---------------- GEMM2: out += rowweight * (act @ Wd), fp32 atomics, no y buffer
__global__ __launch_bounds__(256, 3)
void gemm2_kernel(const u16* __restrict__ act, const u16* __restrict__ wdp,
                  float* __restrict__ out, const int* __restrict__ ctrl, int tile0) {
  __shared__ u16 Al[TM * BK];
  __shared__ u16 Bl[TM * BK];
  int t = tile0 + blockIdx.x;
  if (t >= ctrl[CI_NTILES]) return;
  int e = ctrl[CI_TILE_E + t];
  int row0 = t << 7;
  int row0l = blockIdx.x << 7;
  int col0 = blockIdx.y * TM;             // over C
  const u16* D = wdp + (size_t)e * (I_DIM * C_DIM);
  int tid = threadIdx.x;
  int lane = tid & 63, wv = tid >> 6;
  int lsub = lane >> 3, lchk = lane & 7;
  int co = (lchk ^ lsub) * 8;
  const u16* abase = act + (size_t)(row0l + wv * 32 + lsub) * I_DIM + co;
  size_t boff = (size_t)(col0 + wv * 32 + lsub) * I_DIM + lchk * 8;
  int ldst = wv * 2048;

  f32x4 acc[4][4];
#pragma unroll
  for (int m = 0; m < 4; m++)
#pragma unroll
    for (int n = 0; n < 4; n++) {
      f32x4 z = {0.f, 0.f, 0.f, 0.f};
      acc[m][n] = z;
    }
  int lr = lane & 15, lq = lane >> 4;
  int rh = (wv & 1) * 64, chh = (wv >> 1) * 64;

  for (int kk = 0; kk < I_DIM; kk += BK) {
#pragma unroll
    for (int j = 0; j < 4; j++) {
      dma16(abase + (size_t)j * 8 * I_DIM + kk, Al + ldst + j * 512);
      dma16(D + boff + j * (8 * I_DIM) + kk,    Bl + ldst + j * 512);
    }
    __syncthreads();
#pragma unroll
    for (int s = 0; s < 2; s++) {
      int cidx = s * 4 + lq;
      short8 af[4], bf_[4];
#pragma unroll
      for (int m = 0; m < 4; m++) {
        int r = rh + m * 16 + lr;
        af[m] = *(const short8*)&Al[r * 64 + ((cidx ^ (r & 7)) * 8)];
      }
#pragma unroll
      for (int n = 0; n < 4; n++) {
        int i = chh + n * 16 + lr;
        bf_[n] = *(const short8*)&Bl[i * 64 + ((cidx ^ (i & 7)) * 8)];
      }
#pragma unroll
      for (int m = 0; m < 4; m++)
#pragma unroll
        for (int n = 0; n < 4; n++)
          acc[m][n] = __builtin_amdgcn_mfma_f32_16x16x32_bf16(af[m], bf_[n], acc[m][n], 0, 0, 0);
    }
    __syncthreads();
  }
  const int* perm = ctrl + CI_PERM;
  const float* rw = (const float*)(ctrl + CI_RW);
#pragma unroll
  for (int m = 0; m < 4; m++)
#pragma unroll
    for (int rg = 0; rg < 4; rg++) {
      int rgrow = row0 + rh + m * 16 + lq * 4 + rg;
      int tokn = perm[rgrow];
      if (tokn < 0) continue;              // padding row
      float w = rw[rgrow];
      float* obase = out + (size_t)tokn * C_DIM + col0 + chh + lr;
#pragma unroll
      for (int n = 0; n < 4; n++)
        atomicAdd(obase + n * 16, acc[m][n][rg] * w);
    }
}

extern "C" void kernel_launch(void* const* d_in, const int* in_sizes, int n_in,
                              void* d_out, int out_size, void* d_ws, size_t ws_size,
                              hipStream_t stream) {
  (void)in_sizes; (void)n_in; (void)out_size; (void)ws_size;
  const float* x     = (const float*)d_in[0];
  const float* wgate = (const float*)d_in[1];
  const float* ebias = (const float*)d_in[2];
  const float* wg    = (const float*)d_in[3];
  const float* wu    = (const float*)d_in[4];
  const float* wd    = (const float*)d_in[5];
  const float* swg   = (const float*)d_in[6];
  const float* swu   = (const float*)d_in[7];
  const float* swd   = (const float*)d_in[8];
  float* out = (float*)d_out;
  char* ws = (char*)d_ws;
  int* ctrl = (int*)ws;
  u16* xb  = (u16*)(ws + XB_OFF);
  u16* wgu = (u16*)(ws + WGU_OFF);
  u16* wdp = (u16*)(ws + WDP_OFF);
  u16* act = (u16*)(ws + ACT_OFF);

  hipMemsetAsync(ws, 0, 256, stream);                           // expert counts = 0
  hipMemsetAsync(ws + (size_t)CI_PERM * 4, 0xFF, 51200 * 4, stream);  // perm = -1
  hipMemsetAsync(d_out, 0, (size_t)N_TOK * C_DIM * 4, stream);  // out = 0 (atomic target)
  router_kernel<<<N_TOK / 16, 256, 0, stream>>>(x, wgate, ebias, ctrl, xb);
  tiles_kernel<<<1, 64, 0, stream>>>(ctrl);
  scatter_kernel<<<N_TOK / 256, 256, 0, stream>>>(ctrl);
  convert_kernel<<<34 * 48 + 17 * 24, 256, 0, stream>>>(wg, wu, wd, swg, swu, swd, wgu, wdp);
  for (int p = 0; p < 2; p++) {
    gemm1_kernel<<<dim3(PASS_T, I_DIM / TM), 256, 0, stream>>>(xb, wgu, act, ctrl, p * PASS_T);
    gemm2_kernel<<<dim3(PASS_T, C_DIM / TM), 256, 0, stream>>>(act, wdp, out, ctrl, p * PASS_T);
  }
}